// Round 6
// baseline (157.865 us; speedup 1.0000x reference)
//
#include <hip/hip_runtime.h>
#include <hip/hip_bf16.h>

// LoRA-factored 3x3 conv. out fp32 (proven R3). Inputs runtime-detected fp32/bf16.
// x: [16,128,56,56], A: [256,16], B: [16,1152] -> out: [16,256,56,56] fp32
// R5 post-mortem: VALU path latency-bound at 63us, fp32-VALU floor ~20us.
// This round: stage-1 on MFMA (bf16 16x16x32), becomes write-bound (~10us floor).
// Pipeline: transform_x (NCHW->padded NHWC bf16) -> prep_frags -> lora_mfma.
// Fallback to proven R5 kernel if ws_size too small.

#define Bn 16
#define Cc 128
#define Hh 56
#define Ww 56
#define Ll (Hh * Ww)      // 3136
#define Rr 16
#define Oo 256
#define KF (Cc * 9)       // 1152
#define HP 58             // padded rows: hp = h_in+1, rows 0 and 57 are zero
#define WP 66             // padded cols: wp = w_in+1, cols 0 and 57..65 are zero

typedef short v8s __attribute__((ext_vector_type(8)));
typedef float v4f __attribute__((ext_vector_type(4)));

#define XT_ELEMS ((size_t)Bn * HP * WP * Cc)   // 7,839,744 bf16
#define BFRAG_ELEMS (9 * 4 * 64 * 8)           // 18,432 bf16
#define AFP2_ELEMS (Oo * Rr)                   // 4,096 fp32

__device__ __forceinline__ float bf16_bits(unsigned short u) {
    return __uint_as_float(((unsigned)u) << 16);
}
__device__ __forceinline__ unsigned short f_to_bf16(float f) {
    __hip_bfloat16 h = __float2bfloat16(f);   // RNE
    return *reinterpret_cast<unsigned short*>(&h);
}
template<bool BF>
__device__ __forceinline__ float ld(const void* __restrict__ p, size_t i) {
    if constexpr (BF) return bf16_bits(((const unsigned short*)p)[i]);
    else              return ((const float*)p)[i];
}
// bf16-packed: bits14..7 of each dword = bf16 exponent (~[96,144]) -> 32/32 hits.
// fp32: uniform mantissa bits -> ~6/32. Threshold 20. (Proven R3-R5.)
__device__ __forceinline__ bool detect_bf16(const void* __restrict__ p) {
    const unsigned* w = (const unsigned*)p;
    int c = 0;
#pragma unroll
    for (int i = 0; i < 32; ++i) {
        const unsigned e = (w[i] >> 7) & 0xFFu;
        c += (e >= 96u && e <= 144u) ? 1 : 0;
    }
    return c >= 20;
}

// ---------------- kernel 1: x -> padded NHWC bf16 ----------------
// xT[b][hp][wp][c], zero at hp=0,57 and wp=0,57..65. Contiguous ushort writes.
__global__ __launch_bounds__(256) void transform_x(const void* __restrict__ x,
                                                   unsigned short* __restrict__ xT)
{
    const bool xb = detect_bf16(x);
    const int hp = blockIdx.x;    // 0..57
    const int b  = blockIdx.y;
    const int h  = hp - 1;
    const bool rowok = (h >= 0) && (h < Hh);
    unsigned short* dst = xT + ((size_t)(b * HP + hp)) * WP * Cc;
    for (int t = threadIdx.x; t < WP * Cc; t += 256) {
        const int wp = t >> 7;        // /128
        const int c  = t & 127;
        const int w  = wp - 1;
        unsigned short v = 0;
        if (rowok && (unsigned)w < (unsigned)Ww) {
            const size_t idx = ((size_t)(b * Cc + c)) * Ll + (size_t)(h * Ww + w);
            v = xb ? ((const unsigned short*)x)[idx]
                   : f_to_bf16(((const float*)x)[idx]);
        }
        dst[t] = v;
    }
}

// ---------------- kernel 2: B -> MFMA A-operand fragments; A -> fp32 ----------------
// Bfrag[i][kk][lane][j] = B[r = lane&15][ c = kk*32 + quad*8 + j ][tap i]  (bf16)
// A-operand layout for mfma_f32_16x16x32_bf16: A[m=lane&15][k=quad*8+j].
__global__ __launch_bounds__(256) void prep_frags(const void* __restrict__ A,
                                                  const void* __restrict__ Bm,
                                                  unsigned short* __restrict__ Bfrag,
                                                  float* __restrict__ Afp2)
{
    const bool ab = detect_bf16(A);
    const bool bb = detect_bf16(Bm);
    const int t = blockIdx.x * 256 + threadIdx.x;
    if (t < BFRAG_ELEMS) {
        const int j    = t & 7;
        const int lane = (t >> 3) & 63;
        const int kk   = (t >> 9) & 3;
        const int i    = t >> 11;            // 0..8
        const int r    = lane & 15;
        const int q    = (lane >> 4) & 3;
        const int c    = kk * 32 + q * 8 + j;
        const float v  = bb ? bf16_bits(((const unsigned short*)Bm)[r * KF + c * 9 + i])
                            : ((const float*)Bm)[r * KF + c * 9 + i];
        Bfrag[t] = f_to_bf16(v);
    }
    if (t < AFP2_ELEMS) {
        Afp2[t] = ab ? bf16_bits(((const unsigned short*)A)[t])
                     : ((const float*)A)[t];
    }
}

// ---------------- kernel 3: main MFMA kernel ----------------
// Block = (h, b), 4 waves; wave wv handles pixel tile w0 = wv*16 of row h.
// Stage1: acc[r=quad*4+reg][n=lane&15] += sum over 9 taps x 4 k-steps of
//         mfma(Bfrag(A-op, m=r), xfrag(B-op, k=quad*8+j -> c, n -> pixel)).
// Stage2: C-frag -> LDS (per-wave, no barrier) -> VALU: lane (n, q) does
//         o = q*64..q*64+63, 16 FMA each, quad-broadcast A loads, coalesced stores.
__global__ __launch_bounds__(256) void lora_mfma(const unsigned short* __restrict__ xT,
                                                 const unsigned short* __restrict__ Bfrag,
                                                 const float* __restrict__ Afp2,
                                                 float* __restrict__ out)
{
    __shared__ float tmp2[4][16][20];   // [wave][pixel n][r], pad 20 for banks; 5 KB

    const int tid  = threadIdx.x;
    const int lane = tid & 63;
    const int wv   = tid >> 6;       // tile: w0 = wv*16
    const int n    = lane & 15;      // pixel within tile
    const int q    = (lane >> 4) & 3;
    const int h    = blockIdx.x;     // 0..55
    const int b    = blockIdx.y;

    // per-lane x base: hp = h + dh (dh 0..2), wp = wv*16 + n + dw, c = kk*32 + q*8 + j
    const int wp0 = wv * 16 + n;
    const size_t xrow0 = (((size_t)(b * HP + h)) * WP + wp0) * Cc + q * 8;

    v4f acc = {0.f, 0.f, 0.f, 0.f};
    const v8s* bfp = (const v8s*)Bfrag;

#pragma unroll
    for (int dh = 0; dh < 3; ++dh) {
        const unsigned short* xr = xT + xrow0 + (size_t)dh * (WP * Cc);
#pragma unroll
        for (int dw = 0; dw < 3; ++dw) {
            const int i = dh * 3 + dw;
#pragma unroll
            for (int kk = 0; kk < 4; ++kk) {
                v8s xf = *(const v8s*)(xr + dw * Cc + kk * 32);   // 16B, aligned
                v8s bf = bfp[(i * 4 + kk) * 64 + lane];           // 16B, coalesced
                acc = __builtin_amdgcn_mfma_f32_16x16x32_bf16(bf, xf, acc, 0, 0, 0);
            }
        }
    }

    // C-frag -> LDS: lane holds r = q*4..q*4+3 for pixel n. 16B-aligned (20*4=80, 80%16==0).
    *(v4f*)&tmp2[wv][n][q * 4] = acc;
    // same-wave read-back (compiler inserts lgkmcnt wait; no barrier needed)
    const v4f t0 = *(const v4f*)&tmp2[wv][n][0];
    const v4f t1 = *(const v4f*)&tmp2[wv][n][4];
    const v4f t2 = *(const v4f*)&tmp2[wv][n][8];
    const v4f t3 = *(const v4f*)&tmp2[wv][n][12];
    float tv[16] = {t0.x, t0.y, t0.z, t0.w, t1.x, t1.y, t1.z, t1.w,
                    t2.x, t2.y, t2.z, t2.w, t3.x, t3.y, t3.z, t3.w};

    // stage 2: this lane -> pixel (h, w0+n), output channels q*64 .. q*64+63
    const int w = wv * 16 + n;
    const bool wok = (w < Ww);
    float* obase = out + ((size_t)b * Oo + q * 64) * Ll + (size_t)(h * Ww + w);
    const v4f* A4 = (const v4f*)Afp2;   // A[o][r] as 4x v4f per o

#pragma unroll 8
    for (int oi = 0; oi < 64; ++oi) {
        const int o = q * 64 + oi;
        const v4f a0 = A4[o * 4 + 0];
        const v4f a1 = A4[o * 4 + 1];
        const v4f a2 = A4[o * 4 + 2];
        const v4f a3 = A4[o * 4 + 3];
        float s = a0.x * tv[0]  + a0.y * tv[1]  + a0.z * tv[2]  + a0.w * tv[3]
                + a1.x * tv[4]  + a1.y * tv[5]  + a1.z * tv[6]  + a1.w * tv[7]
                + a2.x * tv[8]  + a2.y * tv[9]  + a2.z * tv[10] + a2.w * tv[11]
                + a3.x * tv[12] + a3.y * tv[13] + a3.z * tv[14] + a3.w * tv[15];
        if (wok) obase[(size_t)oi * Ll] = s;
    }
}

// ================= R5 fallback path (proven, 63us) =================
__global__ __launch_bounds__(256) void r5_prep(const void* __restrict__ A,
                                               const void* __restrict__ Bm,
                                               float* __restrict__ Bt,
                                               float* __restrict__ Afp)
{
    const bool ab = detect_bf16(A);
    const bool bb = detect_bf16(Bm);
    const int i = blockIdx.x * 256 + threadIdx.x;
    if (i < KF * Rr) {
        const int k = i >> 4, r = i & 15;
        Bt[i] = bb ? bf16_bits(((const unsigned short*)Bm)[r * KF + k])
                   : ((const float*)Bm)[r * KF + k];
    }
    if (i < Oo * Rr) {
        Afp[i] = ab ? bf16_bits(((const unsigned short*)A)[i])
                    : ((const float*)A)[i];
    }
}

template<bool XB>
__device__ __forceinline__ void r5_body(const void* __restrict__ x,
                                        const float* __restrict__ Bt,
                                        const float* __restrict__ Afp,
                                        float* __restrict__ out,
                                        float (* __restrict__ part)[Rr][64],
                                        float (* __restrict__ tmp2)[17])
{
    const int tid  = threadIdx.x;
    const int lane = tid & 63;
    const int wv   = __builtin_amdgcn_readfirstlane(tid >> 6);
    const int cs   = wv & 7;
    const int rh   = wv >> 3;
    const int h    = blockIdx.x;
    const int b    = blockIdx.y;
    const int w    = lane;
    const bool wok = (w < Ww);

    float acc[8] = {0.f,0.f,0.f,0.f,0.f,0.f,0.f,0.f};
    const size_t xbase = (size_t)b * Cc * Ll;

    for (int cc = 0; cc < 16; ++cc) {
        const int c = cs * 16 + cc;
        float xv[9];
#pragma unroll
        for (int dh = 0; dh < 3; ++dh) {
            const int hh = h + dh - 1;
            const bool hok = (hh >= 0) & (hh < Hh);
            const size_t rowb = xbase + (size_t)c * Ll + (size_t)(hh * Ww);
#pragma unroll
            for (int dw = 0; dw < 3; ++dw) {
                const int ww = w + dw - 1;
                const bool ok = hok & (ww >= 0) & (ww < Ww);
                xv[dh * 3 + dw] = ok ? ld<XB>(x, rowb + ww) : 0.0f;
            }
        }
        const float* bt = Bt + (size_t)(c * 9) * Rr + rh * 8;
#pragma unroll
        for (int i = 0; i < 9; ++i) {
#pragma unroll
            for (int j = 0; j < 8; ++j)
                acc[j] += bt[(size_t)i * Rr + j] * xv[i];
        }
    }
#pragma unroll
    for (int j = 0; j < 8; ++j) part[cs][rh * 8 + j][lane] = acc[j];
    __syncthreads();
    {
        const int r  = tid >> 6;
        const int px = tid & 63;
        float s = 0.f;
#pragma unroll
        for (int s8 = 0; s8 < 8; ++s8) s += part[s8][r][px];
        tmp2[px][r] = s;
    }
    __syncthreads();
    float tv[Rr];
#pragma unroll
    for (int r = 0; r < Rr; ++r) tv[r] = tmp2[lane][r];
    const size_t obase = (size_t)b * Oo * Ll + (size_t)(h * Ww) + (size_t)w;
#pragma unroll
    for (int j = 0; j < 16; ++j) {
        const int o = wv * 16 + j;
        const float* Ao = Afp + (size_t)o * Rr;
        float s = 0.f;
#pragma unroll
        for (int r = 0; r < Rr; ++r) s += Ao[r] * tv[r];
        if (wok) out[obase + (size_t)o * Ll] = s;
    }
}

__global__ __launch_bounds__(1024, 8) void r5_fused(const void* __restrict__ x,
                                                    const float* __restrict__ Bt,
                                                    const float* __restrict__ Afp,
                                                    float* __restrict__ out)
{
    __shared__ float part[8][Rr][64];
    __shared__ float tmp2[64][17];
    if (detect_bf16(x)) r5_body<true >(x, Bt, Afp, out, part, tmp2);
    else                r5_body<false>(x, Bt, Afp, out, part, tmp2);
}

extern "C" void kernel_launch(void* const* d_in, const int* in_sizes, int n_in,
                              void* d_out, int out_size, void* d_ws, size_t ws_size,
                              hipStream_t stream) {
    const void* x  = d_in[0];
    const void* A  = d_in[1];
    const void* Bm = d_in[2];
    for (int i = 0; i < n_in && i < 3; ++i) {
        const int s = in_sizes[i];
        if      (s == Bn * Cc * Ll) x  = d_in[i];
        else if (s == Oo * Rr)      A  = d_in[i];
        else if (s == Rr * KF)      Bm = d_in[i];
    }
    float* out = (float*)d_out;

    const size_t need_mfma = XT_ELEMS * 2 + BFRAG_ELEMS * 2 + AFP2_ELEMS * 4; // 15,732,736
    const size_t need_r5   = (size_t)(KF * Rr + Oo * Rr) * sizeof(float);     // 90,112

    if (ws_size >= need_mfma) {
        unsigned short* xT    = (unsigned short*)d_ws;
        unsigned short* Bfrag = xT + XT_ELEMS;
        float*          Afp2  = (float*)(Bfrag + BFRAG_ELEMS);
        transform_x<<<dim3(HP, Bn), 256, 0, stream>>>(x, xT);
        prep_frags<<<dim3((BFRAG_ELEMS + 255) / 256), 256, 0, stream>>>(A, Bm, Bfrag, Afp2);
        lora_mfma<<<dim3(Hh, Bn), 256, 0, stream>>>(xT, Bfrag, Afp2, out);
    } else if (ws_size >= need_r5) {
        float* Bt  = (float*)d_ws;
        float* Afp = Bt + KF * Rr;
        r5_prep<<<dim3((KF * Rr + 255) / 256), 256, 0, stream>>>(A, Bm, Bt, Afp);
        r5_fused<<<dim3(Hh, Bn), 1024, 0, stream>>>(x, Bt, Afp, out);
    }
}

// Round 7
// 133.572 us; speedup vs baseline: 1.1819x; 1.1819x over previous
//
#include <hip/hip_runtime.h>
#include <hip/hip_bf16.h>

// LoRA-factored 3x3 conv. out fp32 (proven R3). Inputs runtime-detected fp32/bf16.
// x: [16,128,56,56], A: [256,16], B: [16,1152] -> out: [16,256,56,56] fp32
// R6 post-mortem: lora_mfma latency-bound (MfmaUtil 1.2%, VALU 14%, occ 25%).
// R7: K-split 2-wave blocks (7168 waves), stage-2 moved onto MFMA (proven
// 16x16x32 intrinsic, K zero-padded), transform_x LDS-transposed for coalescing.

#define Bn 16
#define Cc 128
#define Hh 56
#define Ww 56
#define Ll (Hh * Ww)      // 3136
#define Rr 16
#define Oo 256
#define KF (Cc * 9)       // 1152
#define HP 58             // padded rows: hp = h+1 of source row h; rows 0,57 zero
#define WP 66             // padded cols: wp = w+1; cols 0, 57..65 zero

typedef short v8s __attribute__((ext_vector_type(8)));
typedef short v4s __attribute__((ext_vector_type(4)));
typedef float v4f __attribute__((ext_vector_type(4)));

#define XT_ELEMS ((size_t)Bn * HP * WP * Cc)   // 7,839,744 bf16
#define BFRAG_ELEMS (9 * 4 * 64 * 8)           // 18,432 bf16
#define A2_ELEMS (16 * 64 * 8)                 // 8,192 bf16 (16 o-chunks)

__device__ __forceinline__ float bf16_bits(unsigned short u) {
    return __uint_as_float(((unsigned)u) << 16);
}
__device__ __forceinline__ unsigned short f_to_bf16(float f) {
    __hip_bfloat16 h = __float2bfloat16(f);   // RNE
    return *reinterpret_cast<unsigned short*>(&h);
}
template<bool BF>
__device__ __forceinline__ float ld(const void* __restrict__ p, size_t i) {
    if constexpr (BF) return bf16_bits(((const unsigned short*)p)[i]);
    else              return ((const float*)p)[i];
}
// bf16-packed: bits14..7 of each dword = bf16 exponent (~[96,144]) -> 32/32 hits.
// fp32: uniform mantissa -> ~6/32. Threshold 20. (Proven R3-R6.)
__device__ __forceinline__ bool detect_bf16(const void* __restrict__ p) {
    const unsigned* w = (const unsigned*)p;
    int c = 0;
#pragma unroll
    for (int i = 0; i < 32; ++i) {
        const unsigned e = (w[i] >> 7) & 0xFFu;
        c += (e >= 96u && e <= 144u) ? 1 : 0;
    }
    return c >= 20;
}

// ---------------- kernel 1: x -> padded NHWC bf16, LDS-transposed ----------------
// xT[b][hp][wp][c]; reads lane->w (coalesced), writes lane->c (coalesced).
__global__ __launch_bounds__(256) void transform_x(const void* __restrict__ x,
                                                   unsigned short* __restrict__ xT)
{
    __shared__ float lds[64][57];   // [ci][w], pad 57
    const bool xb = detect_bf16(x);
    const int tid = threadIdx.x;
    const int hp = blockIdx.x;    // 0..57
    const int b  = blockIdx.y;
    const int h  = hp - 1;
    unsigned short* dst = xT + ((size_t)(b * HP + hp)) * WP * Cc;

    if (h < 0 || h >= Hh) {       // uniform per block: zero row
        for (int t = tid; t < WP * Cc; t += 256) dst[t] = 0;
        return;
    }
    // zero-pad columns wp=0 and wp=57..65
    for (int t = tid; t < 1280; t += 256) {
        if (t < 128) dst[t] = 0;
        else         dst[57 * 128 + (t - 128)] = 0;
    }
#pragma unroll
    for (int c0 = 0; c0 < Cc; c0 += 64) {
        __syncthreads();
        for (int t = tid; t < 64 * 64; t += 256) {
            const int ci = t >> 6, w = t & 63;
            if (w < Ww)
                lds[ci][w] = ld<false>(x, 0), // placeholder never used
                lds[ci][w] = xb ? bf16_bits(((const unsigned short*)x)[((size_t)(b * Cc + c0 + ci)) * Ll + h * Ww + w])
                                : ((const float*)x)[((size_t)(b * Cc + c0 + ci)) * Ll + h * Ww + w];
        }
        __syncthreads();
        for (int t = tid; t < 56 * 64; t += 256) {
            const int w = t >> 6, ci = t & 63;
            dst[(w + 1) * Cc + c0 + ci] = f_to_bf16(lds[ci][w]);
        }
    }
}

// ---------------- kernel 2: B -> A-op frags (stage1); A -> A-op frags (stage2) ----
// Bfrag[i][kkg][lane][j] = B[r=lane&15][c = kkg*32 + q*8 + j][tap i]  (bf16)
// A2frag[ch][lane][j]: A-op for 16x16x32, m=lane&15 -> o=ch*16+m, k=q*8+j -> r (0 for k>=16)
__global__ __launch_bounds__(256) void prep_frags(const void* __restrict__ A,
                                                  const void* __restrict__ Bm,
                                                  unsigned short* __restrict__ Bfrag,
                                                  unsigned short* __restrict__ A2f)
{
    const bool ab = detect_bf16(A);
    const bool bb = detect_bf16(Bm);
    const int t = blockIdx.x * 256 + threadIdx.x;
    if (t < BFRAG_ELEMS) {
        const int j    = t & 7;
        const int lane = (t >> 3) & 63;
        const int kkg  = (t >> 9) & 3;
        const int i    = t >> 11;            // 0..8
        const int r    = lane & 15;
        const int q    = (lane >> 4) & 3;
        const int c    = kkg * 32 + q * 8 + j;
        const float v  = bb ? bf16_bits(((const unsigned short*)Bm)[r * KF + c * 9 + i])
                            : ((const float*)Bm)[r * KF + c * 9 + i];
        Bfrag[t] = f_to_bf16(v);
    }
    if (t < A2_ELEMS) {
        const int j    = t & 7;
        const int lane = (t >> 3) & 63;
        const int ch   = t >> 9;             // 0..15
        const int m    = lane & 15;
        const int k    = ((lane >> 4) & 3) * 8 + j;
        float v = 0.f;
        if (k < Rr) {
            const int o = ch * 16 + m;
            v = ab ? bf16_bits(((const unsigned short*)A)[o * Rr + k])
                   : ((const float*)A)[o * Rr + k];
        }
        A2f[t] = f_to_bf16(v);
    }
}

// ---------------- kernel 3: main MFMA kernel ----------------
// Block = (tile tw, h, b), 128 threads = 2 waves. Wave cs in {0,1} handles
// channels cs*64..cs*64+63 (18 MFMAs), then the two halves are summed via LDS,
// and each wave runs 8 stage-2 MFMAs (o-chunks cs*8..cs*8+7).
__global__ __launch_bounds__(128, 4) void lora_mfma(const unsigned short* __restrict__ xT,
                                                    const unsigned short* __restrict__ Bfrag,
                                                    const unsigned short* __restrict__ A2f,
                                                    float* __restrict__ out)
{
    __shared__ v4f ex[2][64];                  // 2 KB cross-wave exchange
    __shared__ unsigned short tmpB[2][16][16]; // [wave][n][r] bf16, 1 KB

    const int tid  = threadIdx.x;
    const int lane = tid & 63;
    const int cs   = tid >> 6;       // wave 0/1 = channel half
    const int n    = lane & 15;      // pixel within tile
    const int q    = (lane >> 4) & 3;
    const int tw   = blockIdx.x;     // w-tile 0..3
    const int h    = blockIdx.y;     // 0..55
    const int b    = blockIdx.z;

    // preload stage-2 A fragments (independent -> hidden behind stage 1)
    v8s a2[8];
    {
        const v8s* A2p = (const v8s*)A2f;
#pragma unroll
        for (int j = 0; j < 8; ++j) a2[j] = A2p[(cs * 8 + j) * 64 + lane];
    }

    const int wp0 = tw * 16 + n;
    const size_t xrow0 = (((size_t)(b * HP + h)) * WP + wp0) * Cc + cs * 64 + q * 8;

    v4f acc = {0.f, 0.f, 0.f, 0.f};
    const v8s* bfp = (const v8s*)Bfrag;

#pragma unroll
    for (int dh = 0; dh < 3; ++dh) {
        const unsigned short* xr = xT + xrow0 + (size_t)dh * (WP * Cc);
#pragma unroll
        for (int dw = 0; dw < 3; ++dw) {
            const int i = dh * 3 + dw;
#pragma unroll
            for (int kk = 0; kk < 2; ++kk) {
                v8s xf = *(const v8s*)(xr + dw * Cc + kk * 32);           // 16B
                v8s bf = bfp[(i * 4 + cs * 2 + kk) * 64 + lane];          // 16B coalesced
                acc = __builtin_amdgcn_mfma_f32_16x16x32_bf16(bf, xf, acc, 0, 0, 0);
            }
        }
    }

    // ---- sum the two channel halves (1 barrier) ----
    ex[cs][lane] = acc;
    __syncthreads();
    {
        const v4f other = ex[1 ^ cs][lane];
        acc += other;
    }

    // ---- tmp (C-layout) -> bf16 -> per-wave LDS -> B-operand layout ----
    {
        v4s p;
        p[0] = (short)f_to_bf16(acc[0]);
        p[1] = (short)f_to_bf16(acc[1]);
        p[2] = (short)f_to_bf16(acc[2]);
        p[3] = (short)f_to_bf16(acc[3]);
        *(v4s*)&tmpB[cs][n][q * 4] = p;     // lane holds r = q*4..q*4+3
    }
    // same-wave readback (compiler inserts lgkmcnt wait)
    v8s bop;
    {
        const v8s val = *(const v8s*)&tmpB[cs][n][(q & 1) * 8];  // r = (q&1)*8 .. +7
        const v8s z = {0, 0, 0, 0, 0, 0, 0, 0};
        bop = (q < 2) ? val : z;            // K=32 zero-padded: quads 2,3 contribute 0
    }

    // ---- stage 2: 8 MFMAs, o-chunks ch = cs*8 .. cs*8+7 ----
    const int w = tw * 16 + n;
    const bool wok = (w < Ww);
    const size_t pbase = (size_t)b * Oo * Ll + (size_t)(h * Ww + w);
#pragma unroll
    for (int j = 0; j < 8; ++j) {
        const int ch = cs * 8 + j;
        v4f d = {0.f, 0.f, 0.f, 0.f};
        d = __builtin_amdgcn_mfma_f32_16x16x32_bf16(a2[j], bop, d, 0, 0, 0);
        // D: lane(n,q) reg i -> out[o = ch*16 + q*4 + i][pixel]
        float* ob = out + pbase + (size_t)(ch * 16 + q * 4) * Ll;
#pragma unroll
        for (int i = 0; i < 4; ++i)
            if (wok) ob[(size_t)i * Ll] = d[i];
    }
}

// ================= R5 fallback path (proven) =================
__global__ __launch_bounds__(256) void r5_prep(const void* __restrict__ A,
                                               const void* __restrict__ Bm,
                                               float* __restrict__ Bt,
                                               float* __restrict__ Afp)
{
    const bool ab = detect_bf16(A);
    const bool bb = detect_bf16(Bm);
    const int i = blockIdx.x * 256 + threadIdx.x;
    if (i < KF * Rr) {
        const int k = i >> 4, r = i & 15;
        Bt[i] = bb ? bf16_bits(((const unsigned short*)Bm)[r * KF + k])
                   : ((const float*)Bm)[r * KF + k];
    }
    if (i < Oo * Rr) {
        Afp[i] = ab ? bf16_bits(((const unsigned short*)A)[i])
                    : ((const float*)A)[i];
    }
}

template<bool XB>
__device__ __forceinline__ void r5_body(const void* __restrict__ x,
                                        const float* __restrict__ Bt,
                                        const float* __restrict__ Afp,
                                        float* __restrict__ out,
                                        float (* __restrict__ part)[Rr][64],
                                        float (* __restrict__ tmp2)[17])
{
    const int tid  = threadIdx.x;
    const int lane = tid & 63;
    const int wv   = __builtin_amdgcn_readfirstlane(tid >> 6);
    const int cspl = wv & 7;
    const int rh   = wv >> 3;
    const int h    = blockIdx.x;
    const int b    = blockIdx.y;
    const int w    = lane;
    const bool wok = (w < Ww);

    float acc[8] = {0.f,0.f,0.f,0.f,0.f,0.f,0.f,0.f};
    const size_t xbase = (size_t)b * Cc * Ll;

    for (int cc = 0; cc < 16; ++cc) {
        const int c = cspl * 16 + cc;
        float xv[9];
#pragma unroll
        for (int dh = 0; dh < 3; ++dh) {
            const int hh = h + dh - 1;
            const bool hok = (hh >= 0) & (hh < Hh);
            const size_t rowb = xbase + (size_t)c * Ll + (size_t)(hh * Ww);
#pragma unroll
            for (int dw = 0; dw < 3; ++dw) {
                const int ww = w + dw - 1;
                const bool ok = hok & (ww >= 0) & (ww < Ww);
                xv[dh * 3 + dw] = ok ? ld<XB>(x, rowb + ww) : 0.0f;
            }
        }
        const float* bt = Bt + (size_t)(c * 9) * Rr + rh * 8;
#pragma unroll
        for (int i = 0; i < 9; ++i) {
#pragma unroll
            for (int j = 0; j < 8; ++j)
                acc[j] += bt[(size_t)i * Rr + j] * xv[i];
        }
    }
#pragma unroll
    for (int j = 0; j < 8; ++j) part[cspl][rh * 8 + j][lane] = acc[j];
    __syncthreads();
    {
        const int r  = tid >> 6;
        const int px = tid & 63;
        float s = 0.f;
#pragma unroll
        for (int s8 = 0; s8 < 8; ++s8) s += part[s8][r][px];
        tmp2[px][r] = s;
    }
    __syncthreads();
    float tv[Rr];
#pragma unroll
    for (int r = 0; r < Rr; ++r) tv[r] = tmp2[lane][r];
    const size_t obase = (size_t)b * Oo * Ll + (size_t)(h * Ww) + (size_t)w;
#pragma unroll
    for (int j = 0; j < 16; ++j) {
        const int o = wv * 16 + j;
        const float* Ao = Afp + (size_t)o * Rr;
        float s = 0.f;
#pragma unroll
        for (int r = 0; r < Rr; ++r) s += Ao[r] * tv[r];
        if (wok) out[obase + (size_t)o * Ll] = s;
    }
}

__global__ __launch_bounds__(1024, 8) void r5_fused(const void* __restrict__ x,
                                                    const float* __restrict__ Bt,
                                                    const float* __restrict__ Afp,
                                                    float* __restrict__ out)
{
    __shared__ float part[8][Rr][64];
    __shared__ float tmp2[64][17];
    if (detect_bf16(x)) r5_body<true >(x, Bt, Afp, out, part, tmp2);
    else                r5_body<false>(x, Bt, Afp, out, part, tmp2);
}

extern "C" void kernel_launch(void* const* d_in, const int* in_sizes, int n_in,
                              void* d_out, int out_size, void* d_ws, size_t ws_size,
                              hipStream_t stream) {
    const void* x  = d_in[0];
    const void* A  = d_in[1];
    const void* Bm = d_in[2];
    for (int i = 0; i < n_in && i < 3; ++i) {
        const int s = in_sizes[i];
        if      (s == Bn * Cc * Ll) x  = d_in[i];
        else if (s == Oo * Rr)      A  = d_in[i];
        else if (s == Rr * KF)      Bm = d_in[i];
    }
    float* out = (float*)d_out;

    const size_t need_mfma = XT_ELEMS * 2 + BFRAG_ELEMS * 2 + A2_ELEMS * 2;  // 15,732,480 B
    const size_t need_r5   = (size_t)(KF * Rr + Oo * Rr) * sizeof(float);

    if (ws_size >= need_mfma) {
        unsigned short* xT    = (unsigned short*)d_ws;
        unsigned short* Bfrag = xT + XT_ELEMS;
        unsigned short* A2f   = Bfrag + BFRAG_ELEMS;
        transform_x<<<dim3(HP, Bn), 256, 0, stream>>>(x, xT);
        prep_frags<<<dim3((BFRAG_ELEMS + 255) / 256), 256, 0, stream>>>(A, Bm, Bfrag, A2f);
        lora_mfma<<<dim3(4, Hh, Bn), 128, 0, stream>>>(xT, Bfrag, A2f, out);
    } else if (ws_size >= need_r5) {
        float* Bt  = (float*)d_ws;
        float* Afp = Bt + KF * Rr;
        r5_prep<<<dim3((KF * Rr + 255) / 256), 256, 0, stream>>>(A, Bm, Bt, Afp);
        r5_fused<<<dim3(Hh, Bn), 1024, 0, stream>>>(x, Bt, Afp, out);
    }
}